// Round 4
// baseline (208.977 us; speedup 1.0000x reference)
//
#include <hip/hip_runtime.h>

// Problem constants (match reference)
#define B_ 4
#define N_ 16384
#define M_ 128
#define C_ 128
#define S_ 512
#define ROW_ 131           // 3 + C floats per pooled row
#define NCHUNK_ 256        // 64-point chunks per box (N_/64)
#define RCAP_ 128          // compacted-row cap (fast path covers cnt<=128)
#define RLEN_ 132          // padded compacted row: x,y,z,f0..f127,pad (528 B)
#define KBOX_ 4            // boxes per wave in mask kernel

// Workspace layout (bytes)
#define WS_MASKS_OFF 0u
#define WS_JTAB_OFF  1048576u                        // 512 * 516 ints
#define WS_HDR_OFF   (WS_JTAB_OFF + 512u*516u*4u)    // 512 ints (+pad)
#define WS_IDXG_OFF  (WS_HDR_OFF + 4096u)            // 512*512 ints (rare path)
#define WS_ROWS_OFF  (WS_IDXG_OFF + 512u*512u*4u)    // 512*128*132 floats

typedef float f4_t __attribute__((ext_vector_type(4)));

// ---------------------------------------------------------------------------
// Phase A: per-(box, chunk) in-box bitmask via wave ballot. (unchanged, R7)
// ---------------------------------------------------------------------------
__global__ __launch_bounds__(256) void mask_kernel(
    const float* __restrict__ points,        // (B, N, 3)
    const float* __restrict__ boxes,         // (B*M, 7)
    unsigned long long* __restrict__ masks)  // (B*M, NCHUNK_)
{
    const int gwave = blockIdx.x * 4 + (threadIdx.x >> 6);
    const int lane  = threadIdx.x & 63;
    const int grp   = gwave >> 4;            // box-group [0, B*M/KBOX_)
    const int seg   = gwave & 15;            // 16 chunks per segment
    const int bm0   = grp * KBOX_;
    const int b     = bm0 >> 7;              // batch (shared by the 4 boxes)

    const float* pb = points + (size_t)b * N_ * 3;
    float px[16], py[16], pz[16];
    #pragma unroll
    for (int k = 0; k < 16; ++k) {
        const int i = (seg * 16 + k) * 64 + lane;
        px[k] = pb[i*3+0]; py[k] = pb[i*3+1]; pz[k] = pb[i*3+2];
    }

    for (int kb = 0; kb < KBOX_; ++kb) {
        const int bm = bm0 + kb;
        const float* bx = boxes + bm * 7;
        const float cx = bx[0], cy = bx[1], czb = bx[2];
        const float dx = bx[3], dy = bx[4], dzv = bx[5], rz = bx[6];
        // fp32 reference semantics: no FMA contraction; trig via double->fp32
        const float cz   = __fadd_rn(czb, __fmul_rn(0.5f, dzv));
        const float cosa = (float)cos(-(double)rz);
        const float sina = (float)sin(-(double)rz);
        const float hdx = 0.5f * dx, hdy = 0.5f * dy, hdz = 0.5f * dzv;

        #pragma unroll
        for (int k = 0; k < 16; ++k) {
            const float sx = __fsub_rn(px[k], cx);
            const float sy = __fsub_rn(py[k], cy);
            const float lx = __fsub_rn(__fmul_rn(sx, cosa), __fmul_rn(sy, sina));
            const float ly = __fadd_rn(__fmul_rn(sx, sina), __fmul_rn(sy, cosa));
            const bool pred = (fabsf(__fsub_rn(pz[k], cz)) <= hdz) &&
                              (lx > -hdx) && (lx < hdx) &&
                              (ly > -hdy) && (ly < hdy);
            const unsigned long long m = __ballot(pred);
            if (lane == 0) masks[(size_t)bm * NCHUNK_ + seg * 16 + k] = m;
        }
    }
}

// ---------------------------------------------------------------------------
// P1 resolve — R12: scan + expand (proven R7 logic), then materialize to ws:
// jtab[s]=s%cnt, cnt header, flags, and compacted source rows (528 B each,
// <=128; avg ~27). Tiny LDS (2 KB) -> high occupancy, runs in a few µs.
// ---------------------------------------------------------------------------
__global__ __launch_bounds__(256) void resolve_kernel(
    const float* __restrict__ points,        // (B, N, 3)
    const float* __restrict__ feats,         // (B, N, C)
    const unsigned long long* __restrict__ masks,
    int* __restrict__ jtab_g,                // (B*M, 516)
    int* __restrict__ hdr_g,                 // (B*M,) cnt_eff
    int* __restrict__ idx_g,                 // (B*M, S) rare-path indices
    float* __restrict__ rows_g,              // (B*M, RCAP_, RLEN_)
    float* __restrict__ flags_out)           // (B*M,)
{
    const int bm   = blockIdx.x;
    const int b    = bm >> 7;
    const int tid  = threadIdx.x;
    const int w    = tid >> 6;
    const int lane = tid & 63;

    __shared__ int s_wsum[4];
    __shared__ int s_idx[S_];

    // --- mask word + popcount + wave shuffle-scan ---
    const unsigned long long m0 = masks[(size_t)bm * NCHUNK_ + tid];
    const int c = __popcll(m0);
    int incl = c;
    #pragma unroll
    for (int d = 1; d < 64; d <<= 1) {
        const int t = __shfl_up(incl, d, 64);
        if (lane >= d) incl += t;
    }
    if (lane == 63) s_wsum[w] = incl;
    __syncthreads();
    const int w0 = s_wsum[0], w1 = s_wsum[1], w2 = s_wsum[2], w3 = s_wsum[3];
    const int woff  = (w > 0 ? w0 : 0) + (w > 1 ? w1 : 0) + (w > 2 ? w2 : 0);
    const int total = w0 + w1 + w2 + w3;
    int pos = incl - c + woff;               // exclusive prefix (ordered)

    // --- expand ordered in-box indices ---
    if (c > 0 && pos < S_) {
        unsigned long long m = m0;
        while (m && pos < S_) {
            const int bit = __ffsll((unsigned long long)m) - 1;
            m &= m - 1;
            s_idx[pos++] = tid * 64 + bit;
        }
    }

    const int cnt_eff = total < S_ ? total : S_;
    const int denom   = cnt_eff > 0 ? cnt_eff : 1;

    // --- jtab + header + flag (independent of s_idx contents) ---
    for (int s = tid; s <= S_; s += 256)
        jtab_g[bm * 516 + s] = (s < S_) ? (int)((unsigned)s % (unsigned)denom) : 0;
    if (tid == 0) {
        hdr_g[bm] = cnt_eff;
        flags_out[bm] = (total == 0) ? 1.0f : 0.0f;
    }
    __syncthreads();                         // s_idx ready

    if (total == 0) return;

    // --- compacted rows: [x,y,z,f0..f127,pad] per unique row ---
    const int T = cnt_eff < RCAP_ ? cnt_eff : RCAP_;
    float* rb = rows_g + (size_t)bm * (RCAP_ * RLEN_);
    for (int t = tid; t < T * RLEN_; t += 256) {
        const int u   = (unsigned)t / (unsigned)RLEN_;   // magic-mul
        const int col = t - u * RLEN_;
        const size_t pbase = (size_t)b * N_ + (unsigned)s_idx[u];
        float v = 0.0f;
        if (col < 3)          v = points[pbase * 3 + col];
        else if (col < ROW_)  v = feats[pbase * C_ + (col - 3)];
        rb[t] = v;                            // coalesced dword stores
    }
    // rare path (cnt > RCAP_): dump full index table
    if (cnt_eff > RCAP_)
        for (int j = tid; j < cnt_eff; j += 256) idx_g[bm * S_ + j] = s_idx[j];
}

// ---------------------------------------------------------------------------
// P2 streamer — R12: fill-like pure write stream. Zero LDS, zero barriers,
// no divergence; 2048 blocks (4 per box) x 256 threads -> 8 blocks/CU TLP.
// Per float4: 2 L1-hot jtab dwords + 4 L2/L3-hot row dwords + 1 dwordx4 store.
// This copies the harness fill's profile (6.35 TB/s at low occupancy) as
// closely as the mandatory indirection allows.
// ---------------------------------------------------------------------------
__global__ __launch_bounds__(256) void stream_kernel(
    const float* __restrict__ points,        // (B, N, 3)   rare path only
    const float* __restrict__ feats,         // (B, N, C)   rare path only
    const int* __restrict__ jtab_g,          // (B*M, 516)
    const int* __restrict__ hdr_g,           // (B*M,)
    const int* __restrict__ idx_g,           // (B*M, S)
    const float* __restrict__ rows_g,        // (B*M, RCAP_, RLEN_)
    float* __restrict__ out)                 // (B, M, S, 131)
{
    const int blk = blockIdx.x;
    const int bm  = blk >> 2;                // box
    const int seg = blk & 3;                 // quarter of the box's stream
    const int b   = bm >> 7;
    const int tid = threadIdx.x;

    const int h = hdr_g[bm];                 // uniform -> scalar load
    float* ob = out + (size_t)bm * (S_ * ROW_) + seg * 16768;
    const int ebase = seg * 16768;           // element offset within box

    if (h == 0) {                            // empty box: stream zeros
        const f4_t z = {0.0f, 0.0f, 0.0f, 0.0f};
        for (int f = tid; f < 4192; f += 256) *(f4_t*)(ob + 4 * f) = z;
        return;
    }

    const int* jt = jtab_g + bm * 516;
    if (h <= RCAP_) {
        // fast path: compacted rows (L2/L3-resident, ~33 lanes share a row)
        const float* rb = rows_g + (size_t)bm * (RCAP_ * RLEN_);
        #pragma unroll 1
        for (int bt = 0; bt < 2; ++bt) {
            f4_t v[8];
            #pragma unroll
            for (int u2 = 0; u2 < 8; ++u2) {
                const int fl = tid + (bt * 8 + u2) * 256;      // 0..4095
                const int e  = ebase + 4 * fl;
                const unsigned s0 = (unsigned)e / (unsigned)ROW_;  // magic-mul
                const int col0 = e - (int)s0 * ROW_;
                const int ba = jt[s0] * RLEN_, bb = jt[s0 + 1] * RLEN_;
                #pragma unroll
                for (int jj = 0; jj < 4; ++jj) {
                    int col = col0 + jj;
                    const bool cross = col >= ROW_;
                    col = cross ? col - ROW_ : col;
                    v[u2][jj] = rb[(cross ? bb : ba) + col];
                }
            }
            #pragma unroll
            for (int u2 = 0; u2 < 8; ++u2)
                *(f4_t*)(ob + 4 * (tid + (bt * 8 + u2) * 256)) = v[u2];
        }
        if (tid < 96) {                      // tail: fl = 4096 + tid
            const int fl = 4096 + tid;
            const int e  = ebase + 4 * fl;
            const unsigned s0 = (unsigned)e / (unsigned)ROW_;
            const int col0 = e - (int)s0 * ROW_;
            const int ba = jt[s0] * RLEN_, bb = jt[s0 + 1] * RLEN_;
            f4_t v;
            #pragma unroll
            for (int jj = 0; jj < 4; ++jj) {
                int col = col0 + jj;
                const bool cross = col >= ROW_;
                col = cross ? col - ROW_ : col;
                v[jj] = rb[(cross ? bb : ba) + col];
            }
            *(f4_t*)(ob + 4 * fl) = v;
        }
    } else {
        // rare path (cnt > 128): per-dword gather from original arrays
        for (int fl = tid; fl < 4192; fl += 256) {
            const int e = ebase + 4 * fl;
            const unsigned s0 = (unsigned)e / (unsigned)ROW_;
            const int col0 = e - (int)s0 * ROW_;
            f4_t v;
            #pragma unroll
            for (int jj = 0; jj < 4; ++jj) {
                int col = col0 + jj;
                unsigned s = s0;
                if (col >= ROW_) { col -= ROW_; ++s; }
                const int j = jt[s];
                const int idx = idx_g[bm * S_ + j];
                const size_t pbase = (size_t)b * N_ + (unsigned)idx;
                v[jj] = (col < 3) ? points[pbase * 3 + col]
                                  : feats[pbase * C_ + (col - 3)];
            }
            *(f4_t*)(ob + 4 * fl) = v;
        }
    }
}

extern "C" void kernel_launch(void* const* d_in, const int* in_sizes, int n_in,
                              void* d_out, int out_size, void* d_ws, size_t ws_size,
                              hipStream_t stream) {
    const float* points = (const float*)d_in[0];   // (B, N, 3)
    const float* feats  = (const float*)d_in[1];   // (B, N, C)
    const float* boxes  = (const float*)d_in[2];   // (B, M, 7)
    float* out = (float*)d_out;

    char* ws = (char*)d_ws;
    unsigned long long* masks = (unsigned long long*)(ws + WS_MASKS_OFF); // 1 MB
    int*   jtab = (int*)(ws + WS_JTAB_OFF);    // 1.06 MB
    int*   hdr  = (int*)(ws + WS_HDR_OFF);     // 2 KB
    int*   idxg = (int*)(ws + WS_IDXG_OFF);    // 1 MB
    float* rows = (float*)(ws + WS_ROWS_OFF);  // 34.6 MB

    float* flags = out + (size_t)B_ * M_ * S_ * ROW_;

    // Phase A: (512/KBOX_) box-groups x 16 segments = 2048 waves = 512 blocks
    mask_kernel<<<B_ * M_ * 16 / 4 / KBOX_, 256, 0, stream>>>(
        points, boxes, masks);
    // P1 resolve: one 256-thread block per box (tiny LDS, fast)
    resolve_kernel<<<B_ * M_, 256, 0, stream>>>(
        points, feats, masks, jtab, hdr, idxg, rows, flags);
    // P2 stream: 4 blocks per box, pure write stream
    stream_kernel<<<B_ * M_ * 4, 256, 0, stream>>>(
        points, feats, jtab, hdr, idxg, rows, out);
}